// Round 9
// baseline (79.024 us; speedup 1.0000x reference)
//
#include <hip/hip_runtime.h>
#include <hip/hip_cooperative_groups.h>

namespace cg = cooperative_groups;

#define NS    88     // species
#define CCH   128    // channels
#define GY    16     // atom stripes per species in main kernel
#define BCAP  16384  // per-species bucket capacity
#define SB    64     // sort blocks (64*256 = 16384 atoms)

typedef float f32x4 __attribute__((ext_vector_type(4)));

__device__ const int TRI[20][3] = {
    {0,0,0},{0,0,1},{0,0,2},{0,0,3},{0,1,1},{0,1,2},{0,1,3},{0,2,2},{0,2,3},{0,3,3},
    {1,1,1},{1,1,2},{1,1,3},{1,2,2},{1,2,3},{1,3,3},
    {2,2,2},{2,2,3},{2,3,3},
    {3,3,3}};
__device__ const int PAIR[10][2] = {
    {0,0},{0,1},{0,2},{0,3},{1,1},{1,2},{1,3},{2,2},{2,3},{3,3}};

// ---------------- sort phases (R6-verified algorithms) ----------------

__device__ inline void d_sort_p1(const int* __restrict__ species, int N, int b,
                                 int* __restrict__ blockhist) {
    __shared__ int hist[NS];
    int tid = threadIdx.x;
    for (int i = tid; i < NS; i += 256) hist[i] = 0;
    __syncthreads();
    int n = b * 256 + tid;
    if (n < N) atomicAdd(&hist[species[n]], 1);
    __syncthreads();
    for (int i = tid; i < NS; i += 256) blockhist[b * NS + i] = hist[i];
}

__device__ inline void d_sort_p2(const int* __restrict__ species, int N, int b,
                                 const int* __restrict__ blockhist,
                                 int* __restrict__ counts, int* __restrict__ list) {
    __shared__ int boff[NS];
    __shared__ int wh[4][NS];
    int tid = threadIdx.x, lane = tid & 63, w = tid >> 6;
    // inline per-block exclusive scan over earlier blocks (L2-resident table)
    for (int sp = tid; sp < NS; sp += 256) {
        int acc = 0;
        for (int b2 = 0; b2 < b; ++b2) acc += blockhist[b2 * NS + sp];
        boff[sp] = acc;
        if (b == SB - 1) counts[sp] = acc + blockhist[(SB - 1) * NS + sp];
    }
    for (int i = tid; i < 4 * NS; i += 256) ((int*)wh)[i] = 0;
    __syncthreads();
    int n = b * 256 + tid;
    int s = (n < N) ? species[n] : -1;
    if (s >= 0) atomicAdd(&wh[w][s], 1);
    // intra-wave rank via 7-bit ballot equivalence classes (all lanes participate)
    unsigned v = (s >= 0) ? (unsigned)s : 127u;
    unsigned long long eq = ~0ull;
#pragma unroll
    for (int bit = 0; bit < 7; ++bit) {
        unsigned long long bb = __ballot((v >> bit) & 1);
        eq &= ((v >> bit) & 1) ? bb : ~bb;
    }
    int rank = __popcll(eq & ((1ull << lane) - 1));
    __syncthreads();
    if (s >= 0) {
#pragma unroll
        for (int w2 = 0; w2 < 3; ++w2) if (w2 < w) rank += wh[w2][s];
        list[s * BCAP + boff[s] + rank] = n;
    }
}

// ---------------- cooperative sort (one dispatch) + fallback ----------------

__global__ __launch_bounds__(256) void k_sort(
    const int* __restrict__ species, int N,
    int* __restrict__ blockhist, int* __restrict__ counts, int* __restrict__ list) {
    cg::grid_group g = cg::this_grid();
    d_sort_p1(species, N, blockIdx.x, blockhist);
    g.sync();
    d_sort_p2(species, N, blockIdx.x, blockhist, counts, list);
}

__global__ __launch_bounds__(256) void k_sA(
    const int* __restrict__ species, int N, int* __restrict__ blockhist) {
    d_sort_p1(species, N, blockIdx.x, blockhist);
}

__global__ __launch_bounds__(256) void k_sB(
    const int* __restrict__ species, int N, const int* __restrict__ blockhist,
    int* __restrict__ counts, int* __restrict__ list) {
    d_sort_p2(species, N, blockIdx.x, blockhist, counts, list);
}

// ---------------- main kernel: inline table build + contraction ----------------
// Block = 128 threads (one channel each), blockIdx.x = species s, blockIdx.y = stripe.
// Stage A: symmetrized U bases -> LDS (species-independent, rebuilt per block).
// Stage B: per-thread contraction with (s,c) weights -> coef[34] f32x4 in VGPRs.
// Atom loop: R6-verified; next atom's x prefetched; NT loads/stores.

__global__ __launch_bounds__(128, 2) void k_main(
    const float* __restrict__ x,
    const int* __restrict__ list, const int* __restrict__ counts,
    const float* __restrict__ u1_0e, const float* __restrict__ w1_0e,
    const float* __restrict__ u1_1o, const float* __restrict__ w1_1o,
    const float* __restrict__ u2_0e, const float* __restrict__ w2_0e,
    const float* __restrict__ u2_1o, const float* __restrict__ w2_1o,
    const float* __restrict__ u3_0e, const float* __restrict__ w3_0e,
    const float* __restrict__ u3_1o, const float* __restrict__ w3_1o,
    float* __restrict__ out) {
    int s = blockIdx.x;
    int c = threadIdx.x;
    int cnt = counts[s];
    int t = (int)blockIdx.y;
    if (t >= cnt) return;                       // uniform across block

    __shared__ float S3e[20][4];
    __shared__ float S3o[20][6][3];
    __shared__ float S2e[10][2];
    __shared__ float S2o[10][2][3];
    __shared__ float S1e[4];
    __shared__ float S1o[4][3];

    // ---- stage A: symmetrized bases into LDS (536 jobs, 128 threads) ----
    for (int j = c; j < 536; j += 128) {
        if (j < 80) {
            int m = j >> 2, k = j & 3;
            int a = TRI[m][0], b = TRI[m][1], d = TRI[m][2];
            int P[6][3] = {{a,b,d},{a,d,b},{b,a,d},{b,d,a},{d,a,b},{d,b,a}};
            float acc = 0.f;
#pragma unroll
            for (int p = 0; p < 6; ++p)
                acc += u3_0e[((P[p][0] * 4 + P[p][1]) * 4 + P[p][2]) * 4 + k];
            float inv = (a == d) ? (1.f / 6.f) : ((a == b || b == d) ? 0.5f : 1.f);
            S3e[m][k] = acc * inv;
        } else if (j < 440) {
            int r = j - 80;
            int m = r / 18, jj = r % 18, k = jj / 3, i = jj % 3;
            int a = TRI[m][0], b = TRI[m][1], d = TRI[m][2];
            int P[6][3] = {{a,b,d},{a,d,b},{b,a,d},{b,d,a},{d,a,b},{d,b,a}};
            float acc = 0.f;
#pragma unroll
            for (int p = 0; p < 6; ++p)
                acc += u3_1o[(((P[p][0] * 4 + P[p][1]) * 4 + P[p][2]) * 6 + k) * 3 + i];
            float inv = (a == d) ? (1.f / 6.f) : ((a == b || b == d) ? 0.5f : 1.f);
            S3o[m][k][i] = acc * inv;
        } else if (j < 460) {
            int r = j - 440;
            int m = r >> 1, k = r & 1;
            int a = PAIR[m][0], b = PAIR[m][1];
            float acc = u2_0e[(a * 4 + b) * 2 + k];
            if (a != b) acc += u2_0e[(b * 4 + a) * 2 + k];
            S2e[m][k] = acc;
        } else if (j < 520) {
            int r = j - 460;
            int m = r / 6, jj = r % 6, k = jj / 3, i = jj % 3;
            int a = PAIR[m][0], b = PAIR[m][1];
            float acc = u2_1o[((a * 4 + b) * 2 + k) * 3 + i];
            if (a != b) acc += u2_1o[((b * 4 + a) * 2 + k) * 3 + i];
            S2o[m][k][i] = acc;
        } else if (j < 524) {
            int d = j - 520;
            S1e[d] = u1_0e[d];
        } else {
            int r = j - 524;
            S1o[r / 3][r % 3] = u1_1o[r];
        }
    }
    __syncthreads();

    // ---- stage B: per-(s,c) coefficients into VGPRs ----
    float wk3e[4], wk3o[6], wk2e[2], wk2o[2];
#pragma unroll
    for (int k = 0; k < 4; ++k) wk3e[k] = w3_0e[(s * 4 + k) * CCH + c];
#pragma unroll
    for (int k = 0; k < 6; ++k) wk3o[k] = w3_1o[(s * 6 + k) * CCH + c];
#pragma unroll
    for (int k = 0; k < 2; ++k) wk2e[k] = w2_0e[(s * 2 + k) * CCH + c];
#pragma unroll
    for (int k = 0; k < 2; ++k) wk2o[k] = w2_1o[(s * 2 + k) * CCH + c];
    float wk1e = w1_0e[s * CCH + c];
    float wk1o = w1_1o[s * CCH + c];

    f32x4 coef[34];
#pragma unroll
    for (int m = 0; m < 20; ++m) {
        f32x4 row;
        float e = 0.f;
#pragma unroll
        for (int k = 0; k < 4; ++k) e = fmaf(S3e[m][k], wk3e[k], e);
        row.x = e;
#pragma unroll
        for (int i = 0; i < 3; ++i) {
            float o = 0.f;
#pragma unroll
            for (int k = 0; k < 6; ++k) o = fmaf(S3o[m][k][i], wk3o[k], o);
            row[1 + i] = o;
        }
        coef[m] = row;
    }
#pragma unroll
    for (int m = 0; m < 10; ++m) {
        f32x4 row;
        row.x = fmaf(S2e[m][0], wk2e[0], S2e[m][1] * wk2e[1]);
#pragma unroll
        for (int i = 0; i < 3; ++i)
            row[1 + i] = fmaf(S2o[m][0][i], wk2o[0], S2o[m][1][i] * wk2o[1]);
        coef[20 + m] = row;
    }
#pragma unroll
    for (int d = 0; d < 4; ++d) {
        f32x4 row;
        row.x = S1e[d] * wk1e;
#pragma unroll
        for (int i = 0; i < 3; ++i) row[1 + i] = S1o[d][i] * wk1o;
        coef[30 + d] = row;
    }

    // ---- atom loop ----
    const int* bucket = list + s * BCAP;
    int n = bucket[t];
    f32x4 xv = __builtin_nontemporal_load(
        reinterpret_cast<const f32x4*>(x + (size_t)n * 512 + (c << 2)));

    while (true) {
        int tn = t + GY;
        bool more = tn < cnt;
        int nn = 0;
        f32x4 xn = (f32x4)(0.f);
        if (more) {
            nn = bucket[tn];
            xn = __builtin_nontemporal_load(
                reinterpret_cast<const f32x4*>(x + (size_t)nn * 512 + (c << 2)));
        }

        float xa[4] = {xv.x, xv.y, xv.z, xv.w};
        float mono[34];
        int q = 0;
#pragma unroll
        for (int a = 0; a < 4; ++a)
#pragma unroll
        for (int b = a; b < 4; ++b) { mono[20 + q] = xa[a] * xa[b]; ++q; }
        int m3 = 0;
#pragma unroll
        for (int a = 0; a < 4; ++a)
#pragma unroll
        for (int b = a; b < 4; ++b)
#pragma unroll
        for (int d = b; d < 4; ++d) { mono[m3] = mono[20 + (a * (7 - a)) / 2 + b] * xa[d]; ++m3; }
#pragma unroll
        for (int d = 0; d < 4; ++d) mono[30 + d] = xa[d];

        float o0 = 0.f, o1 = 0.f, o2 = 0.f, o3 = 0.f;
#pragma unroll
        for (int m = 0; m < 34; ++m) {
            float mv = mono[m];
            o0 = fmaf(coef[m].x, mv, o0);
            o1 = fmaf(coef[m].y, mv, o1);
            o2 = fmaf(coef[m].z, mv, o2);
            o3 = fmaf(coef[m].w, mv, o3);
        }
        float* orow = out + (size_t)n * 512;
        __builtin_nontemporal_store(o0, orow + c);
        __builtin_nontemporal_store(o1, orow + CCH + 3 * c + 0);
        __builtin_nontemporal_store(o2, orow + CCH + 3 * c + 1);
        __builtin_nontemporal_store(o3, orow + CCH + 3 * c + 2);

        if (!more) break;
        t = tn; n = nn; xv = xn;
    }
}

// ---------------- launch ----------------

extern "C" void kernel_launch(void* const* d_in, const int* in_sizes, int n_in,
                              void* d_out, int out_size, void* d_ws, size_t ws_size,
                              hipStream_t stream) {
    const float* x     = (const float*)d_in[0];
    const float* u1_0e = (const float*)d_in[1];
    const float* w1_0e = (const float*)d_in[2];
    const float* u1_1o = (const float*)d_in[3];
    const float* w1_1o = (const float*)d_in[4];
    const float* u2_0e = (const float*)d_in[5];
    const float* w2_0e = (const float*)d_in[6];
    const float* u2_1o = (const float*)d_in[7];
    const float* w2_1o = (const float*)d_in[8];
    const float* u3_0e = (const float*)d_in[9];
    const float* w3_0e = (const float*)d_in[10];
    const float* u3_1o = (const float*)d_in[11];
    const float* w3_1o = (const float*)d_in[12];
    const int*   spec  = (const int*)d_in[13];
    int N = in_sizes[13];
    float* out = (float*)d_out;

    char* ws = (char*)d_ws;
    int* list      = (int*)ws;                               // NS*BCAP ints
    int* counts    = list + (size_t)NS * BCAP;               // NS ints
    int* blockhist = counts + NS;                            // SB*NS ints

    void* args[] = {(void*)&spec, (void*)&N, (void*)&blockhist,
                    (void*)&counts, (void*)&list};
    hipError_t e = hipLaunchCooperativeKernel((const void*)k_sort, dim3(SB), dim3(256),
                                              args, 0, stream);
    if (e != hipSuccess) {
        k_sA<<<SB, 256, 0, stream>>>(spec, N, blockhist);
        k_sB<<<SB, 256, 0, stream>>>(spec, N, blockhist, counts, list);
    }
    k_main<<<dim3(NS, GY), 128, 0, stream>>>(
        x, list, counts,
        u1_0e, w1_0e, u1_1o, w1_1o,
        u2_0e, w2_0e, u2_1o, w2_1o,
        u3_0e, w3_0e, u3_1o, w3_1o,
        out);
}

// Round 10
// 72.619 us; speedup vs baseline: 1.0882x; 1.0882x over previous
//
#include <hip/hip_runtime.h>

#define NS    88     // species
#define CCH   128    // channels
#define GY    16     // atom stripes per species in main kernel
#define BCAP  16384  // per-species bucket capacity
#define SB    64     // sort blocks (64*256 = 16384 atoms)

typedef float f32x4 __attribute__((ext_vector_type(4)));

__device__ const int TRI[20][3] = {
    {0,0,0},{0,0,1},{0,0,2},{0,0,3},{0,1,1},{0,1,2},{0,1,3},{0,2,2},{0,2,3},{0,3,3},
    {1,1,1},{1,1,2},{1,1,3},{1,2,2},{1,2,3},{1,3,3},
    {2,2,2},{2,2,3},{2,3,3},
    {3,3,3}};
__device__ const int PAIR[10][2] = {
    {0,0},{0,1},{0,2},{0,3},{1,1},{1,2},{1,3},{2,2},{2,3},{3,3}};

// ---------------- sort kernel A: per-block histogram (R6-verified) ----------------

__global__ __launch_bounds__(256) void k_sA(
    const int* __restrict__ species, int N, int* __restrict__ blockhist) {
    __shared__ int hist[NS];
    int tid = threadIdx.x, b = blockIdx.x;
    for (int i = tid; i < NS; i += 256) hist[i] = 0;
    __syncthreads();
    int n = b * 256 + tid;
    if (n < N) atomicAdd(&hist[species[n]], 1);
    __syncthreads();
    for (int i = tid; i < NS; i += 256) blockhist[b * NS + i] = hist[i];
}

// ---------------- sort kernel B: inline scan + ballot-ranked scatter (R9-verified) ----------------

__global__ __launch_bounds__(256) void k_sB(
    const int* __restrict__ species, int N, const int* __restrict__ blockhist,
    int* __restrict__ counts, int* __restrict__ list) {
    __shared__ int boff[NS];
    __shared__ int wh[4][NS];
    int tid = threadIdx.x, b = blockIdx.x, lane = tid & 63, w = tid >> 6;
    for (int sp = tid; sp < NS; sp += 256) {
        int acc = 0;
        for (int b2 = 0; b2 < b; ++b2) acc += blockhist[b2 * NS + sp];
        boff[sp] = acc;
        if (b == SB - 1) counts[sp] = acc + blockhist[(SB - 1) * NS + sp];
    }
    for (int i = tid; i < 4 * NS; i += 256) ((int*)wh)[i] = 0;
    __syncthreads();
    int n = b * 256 + tid;
    int s = (n < N) ? species[n] : -1;
    if (s >= 0) atomicAdd(&wh[w][s], 1);
    unsigned v = (s >= 0) ? (unsigned)s : 127u;
    unsigned long long eq = ~0ull;
#pragma unroll
    for (int bit = 0; bit < 7; ++bit) {
        unsigned long long bb = __ballot((v >> bit) & 1);
        eq &= ((v >> bit) & 1) ? bb : ~bb;
    }
    int rank = __popcll(eq & ((1ull << lane) - 1));
    __syncthreads();
    if (s >= 0) {
#pragma unroll
        for (int w2 = 0; w2 < 3; ++w2) if (w2 < w) rank += wh[w2][s];
        list[s * BCAP + boff[s] + rank] = n;
    }
}

// ---------------- main kernel: inline table build + contraction ----------------
// Block = 128 threads (one channel each), blockIdx.x = species s, blockIdx.y = stripe.
// __launch_bounds__(128, 1): VGPR budget 512 so coef[34] f32x4 (136 VGPRs) stays
// in registers — the (128,2) variants capped VGPRs at 96..120 and spilled coef,
// costing ~25 us/iter pass (R7/R9 evidence).
// Pipeline: bucket index known 2 iterations ahead, x-load in flight 1 ahead.

__global__ __launch_bounds__(128, 1) void k_main(
    const float* __restrict__ x,
    const int* __restrict__ list, const int* __restrict__ counts,
    const float* __restrict__ u1_0e, const float* __restrict__ w1_0e,
    const float* __restrict__ u1_1o, const float* __restrict__ w1_1o,
    const float* __restrict__ u2_0e, const float* __restrict__ w2_0e,
    const float* __restrict__ u2_1o, const float* __restrict__ w2_1o,
    const float* __restrict__ u3_0e, const float* __restrict__ w3_0e,
    const float* __restrict__ u3_1o, const float* __restrict__ w3_1o,
    float* __restrict__ out) {
    int s = blockIdx.x;
    int c = threadIdx.x;
    int cnt = counts[s];
    int t = (int)blockIdx.y;
    if (t >= cnt) return;                       // uniform across block

    __shared__ float S3e[20][4];
    __shared__ float S3o[20][6][3];
    __shared__ float S2e[10][2];
    __shared__ float S2o[10][2][3];
    __shared__ float S1e[4];
    __shared__ float S1o[4][3];

    // ---- stage A: symmetrized bases into LDS (536 jobs, 128 threads) ----
    for (int j = c; j < 536; j += 128) {
        if (j < 80) {
            int m = j >> 2, k = j & 3;
            int a = TRI[m][0], b = TRI[m][1], d = TRI[m][2];
            int P[6][3] = {{a,b,d},{a,d,b},{b,a,d},{b,d,a},{d,a,b},{d,b,a}};
            float acc = 0.f;
#pragma unroll
            for (int p = 0; p < 6; ++p)
                acc += u3_0e[((P[p][0] * 4 + P[p][1]) * 4 + P[p][2]) * 4 + k];
            float inv = (a == d) ? (1.f / 6.f) : ((a == b || b == d) ? 0.5f : 1.f);
            S3e[m][k] = acc * inv;
        } else if (j < 440) {
            int r = j - 80;
            int m = r / 18, jj = r % 18, k = jj / 3, i = jj % 3;
            int a = TRI[m][0], b = TRI[m][1], d = TRI[m][2];
            int P[6][3] = {{a,b,d},{a,d,b},{b,a,d},{b,d,a},{d,a,b},{d,b,a}};
            float acc = 0.f;
#pragma unroll
            for (int p = 0; p < 6; ++p)
                acc += u3_1o[(((P[p][0] * 4 + P[p][1]) * 4 + P[p][2]) * 6 + k) * 3 + i];
            float inv = (a == d) ? (1.f / 6.f) : ((a == b || b == d) ? 0.5f : 1.f);
            S3o[m][k][i] = acc * inv;
        } else if (j < 460) {
            int r = j - 440;
            int m = r >> 1, k = r & 1;
            int a = PAIR[m][0], b = PAIR[m][1];
            float acc = u2_0e[(a * 4 + b) * 2 + k];
            if (a != b) acc += u2_0e[(b * 4 + a) * 2 + k];
            S2e[m][k] = acc;
        } else if (j < 520) {
            int r = j - 460;
            int m = r / 6, jj = r % 6, k = jj / 3, i = jj % 3;
            int a = PAIR[m][0], b = PAIR[m][1];
            float acc = u2_1o[((a * 4 + b) * 2 + k) * 3 + i];
            if (a != b) acc += u2_1o[((b * 4 + a) * 2 + k) * 3 + i];
            S2o[m][k][i] = acc;
        } else if (j < 524) {
            int d = j - 520;
            S1e[d] = u1_0e[d];
        } else {
            int r = j - 524;
            S1o[r / 3][r % 3] = u1_1o[r];
        }
    }
    __syncthreads();

    // ---- stage B: per-(s,c) coefficients into VGPRs ----
    float wk3e[4], wk3o[6], wk2e[2], wk2o[2];
#pragma unroll
    for (int k = 0; k < 4; ++k) wk3e[k] = w3_0e[(s * 4 + k) * CCH + c];
#pragma unroll
    for (int k = 0; k < 6; ++k) wk3o[k] = w3_1o[(s * 6 + k) * CCH + c];
#pragma unroll
    for (int k = 0; k < 2; ++k) wk2e[k] = w2_0e[(s * 2 + k) * CCH + c];
#pragma unroll
    for (int k = 0; k < 2; ++k) wk2o[k] = w2_1o[(s * 2 + k) * CCH + c];
    float wk1e = w1_0e[s * CCH + c];
    float wk1o = w1_1o[s * CCH + c];

    f32x4 coef[34];
#pragma unroll
    for (int m = 0; m < 20; ++m) {
        f32x4 row;
        float e = 0.f;
#pragma unroll
        for (int k = 0; k < 4; ++k) e = fmaf(S3e[m][k], wk3e[k], e);
        row.x = e;
#pragma unroll
        for (int i = 0; i < 3; ++i) {
            float o = 0.f;
#pragma unroll
            for (int k = 0; k < 6; ++k) o = fmaf(S3o[m][k][i], wk3o[k], o);
            row[1 + i] = o;
        }
        coef[m] = row;
    }
#pragma unroll
    for (int m = 0; m < 10; ++m) {
        f32x4 row;
        row.x = fmaf(S2e[m][0], wk2e[0], S2e[m][1] * wk2e[1]);
#pragma unroll
        for (int i = 0; i < 3; ++i)
            row[1 + i] = fmaf(S2o[m][0][i], wk2o[0], S2o[m][1][i] * wk2o[1]);
        coef[20 + m] = row;
    }
#pragma unroll
    for (int d = 0; d < 4; ++d) {
        f32x4 row;
        row.x = S1e[d] * wk1e;
#pragma unroll
        for (int i = 0; i < 3; ++i) row[1 + i] = S1o[d][i] * wk1o;
        coef[30 + d] = row;
    }

    // ---- atom loop, 2-deep index / 1-deep x software pipeline ----
    const int* bucket = list + s * BCAP;
    int n0 = bucket[t];
    f32x4 x0 = __builtin_nontemporal_load(
        reinterpret_cast<const f32x4*>(x + (size_t)n0 * 512 + (c << 2)));
    int t1 = t + GY;
    bool m1 = t1 < cnt;
    int n1 = m1 ? bucket[t1] : n0;
    f32x4 x1 = x0;
    if (m1) x1 = __builtin_nontemporal_load(
        reinterpret_cast<const f32x4*>(x + (size_t)n1 * 512 + (c << 2)));
    int t2 = t1 + GY;
    bool m2 = t2 < cnt;
    int n2 = m2 ? bucket[t2] : n0;

    while (true) {
        // issue prefetches: x for n2 (2 ahead of current), index for t3
        f32x4 x2 = x0;
        if (m2) x2 = __builtin_nontemporal_load(
            reinterpret_cast<const f32x4*>(x + (size_t)n2 * 512 + (c << 2)));
        int t3 = t2 + GY;
        bool m3 = t3 < cnt;
        int n3 = m3 ? bucket[t3] : n0;

        // compute on (n0, x0)
        float xa[4] = {x0.x, x0.y, x0.z, x0.w};
        float mono[34];
        int q = 0;
#pragma unroll
        for (int a = 0; a < 4; ++a)
#pragma unroll
        for (int b = a; b < 4; ++b) { mono[20 + q] = xa[a] * xa[b]; ++q; }
        int m3i = 0;
#pragma unroll
        for (int a = 0; a < 4; ++a)
#pragma unroll
        for (int b = a; b < 4; ++b)
#pragma unroll
        for (int d = b; d < 4; ++d) { mono[m3i] = mono[20 + (a * (7 - a)) / 2 + b] * xa[d]; ++m3i; }
#pragma unroll
        for (int d = 0; d < 4; ++d) mono[30 + d] = xa[d];

        float o0 = 0.f, o1 = 0.f, o2 = 0.f, o3 = 0.f;
#pragma unroll
        for (int m = 0; m < 34; ++m) {
            float mv = mono[m];
            o0 = fmaf(coef[m].x, mv, o0);
            o1 = fmaf(coef[m].y, mv, o1);
            o2 = fmaf(coef[m].z, mv, o2);
            o3 = fmaf(coef[m].w, mv, o3);
        }
        float* orow = out + (size_t)n0 * 512;
        __builtin_nontemporal_store(o0, orow + c);
        __builtin_nontemporal_store(o1, orow + CCH + 3 * c + 0);
        __builtin_nontemporal_store(o2, orow + CCH + 3 * c + 1);
        __builtin_nontemporal_store(o3, orow + CCH + 3 * c + 2);

        if (!m1) break;
        n0 = n1; x0 = x1;
        n1 = n2; x1 = x2; m1 = m2;
        n2 = n3; m2 = m3; t2 = t3;
    }
}

// ---------------- launch ----------------

extern "C" void kernel_launch(void* const* d_in, const int* in_sizes, int n_in,
                              void* d_out, int out_size, void* d_ws, size_t ws_size,
                              hipStream_t stream) {
    const float* x     = (const float*)d_in[0];
    const float* u1_0e = (const float*)d_in[1];
    const float* w1_0e = (const float*)d_in[2];
    const float* u1_1o = (const float*)d_in[3];
    const float* w1_1o = (const float*)d_in[4];
    const float* u2_0e = (const float*)d_in[5];
    const float* w2_0e = (const float*)d_in[6];
    const float* u2_1o = (const float*)d_in[7];
    const float* w2_1o = (const float*)d_in[8];
    const float* u3_0e = (const float*)d_in[9];
    const float* w3_0e = (const float*)d_in[10];
    const float* u3_1o = (const float*)d_in[11];
    const float* w3_1o = (const float*)d_in[12];
    const int*   spec  = (const int*)d_in[13];
    int N = in_sizes[13];
    float* out = (float*)d_out;

    char* ws = (char*)d_ws;
    int* list      = (int*)ws;                               // NS*BCAP ints
    int* counts    = list + (size_t)NS * BCAP;               // NS ints
    int* blockhist = counts + NS;                            // SB*NS ints

    k_sA<<<SB, 256, 0, stream>>>(spec, N, blockhist);
    k_sB<<<SB, 256, 0, stream>>>(spec, N, blockhist, counts, list);
    k_main<<<dim3(NS, GY), 128, 0, stream>>>(
        x, list, counts,
        u1_0e, w1_0e, u1_1o, w1_1o,
        u2_0e, w2_0e, u2_1o, w2_1o,
        u3_0e, w3_0e, u3_1o, w3_1o,
        out);
}

// Round 11
// 53.739 us; speedup vs baseline: 1.4705x; 1.3513x over previous
//
#include <hip/hip_runtime.h>

#define NS    88     // species
#define CCH   128    // channels
#define BCAP  16384  // per-species bucket capacity
#define SB    64     // sort blocks (64*256 = 16384 atoms)
#define STR   6      // atom stripes of AB per species (capacity 768 >> max count)
#define AB    128    // atoms per block

typedef float f32x4 __attribute__((ext_vector_type(4)));

// multiset tables for the table-build kernel (verified R6)
__device__ const int TRI[20][3] = {
    {0,0,0},{0,0,1},{0,0,2},{0,0,3},{0,1,1},{0,1,2},{0,1,3},{0,2,2},{0,2,3},{0,3,3},
    {1,1,1},{1,1,2},{1,1,3},{1,2,2},{1,2,3},{1,3,3},
    {2,2,2},{2,2,3},{2,3,3},
    {3,3,3}};
__device__ const int PAIR[10][2] = {
    {0,0},{0,1},{0,2},{0,3},{1,1},{1,2},{1,3},{2,2},{2,3},{3,3}};

// ---------------- kernel 1: per-block histogram (blocks 0..63) + coef table (64..107) ----------------
// T layout (NEW): [s][m(34)][c(128)][4comp]  (f32x4 row per (s,m,c))
// m: 0..19 cubic (TRI order), 20..29 pairs (PAIR order), 30..33 linear; comp[0]=0e, [1..3]=1o.

__global__ __launch_bounds__(256) void k_sort1(
    const int* __restrict__ species, int N,
    const float* __restrict__ u1_0e, const float* __restrict__ w1_0e,
    const float* __restrict__ u1_1o, const float* __restrict__ w1_1o,
    const float* __restrict__ u2_0e, const float* __restrict__ w2_0e,
    const float* __restrict__ u2_1o, const float* __restrict__ w2_1o,
    const float* __restrict__ u3_0e, const float* __restrict__ w3_0e,
    const float* __restrict__ u3_1o, const float* __restrict__ w3_1o,
    float* __restrict__ T, int* __restrict__ blockhist) {

    int tid = threadIdx.x;

    if (blockIdx.x < SB) {
        __shared__ int hist[NS];
        int b = blockIdx.x;
        for (int i = tid; i < NS; i += 256) hist[i] = 0;
        __syncthreads();
        int n = b * 256 + tid;
        if (n < N) atomicAdd(&hist[species[n]], 1);
        __syncthreads();
        for (int i = tid; i < NS; i += 256) blockhist[b * NS + i] = hist[i];
        return;
    }

    __shared__ float S3e[20][4];
    __shared__ float S3o[20][6][3];
    __shared__ float S2e[10][2];
    __shared__ float S2o[10][2][3];
    __shared__ float S1e[4];
    __shared__ float S1o[4][3];

    // stage A: symmetrized bases into LDS (536 jobs, 256 threads)
    for (int t = tid; t < 536; t += 256) {
        if (t < 80) {
            int m = t >> 2, k = t & 3;
            int a = TRI[m][0], b = TRI[m][1], d = TRI[m][2];
            int P[6][3] = {{a,b,d},{a,d,b},{b,a,d},{b,d,a},{d,a,b},{d,b,a}};
            float acc = 0.f;
#pragma unroll
            for (int p = 0; p < 6; ++p)
                acc += u3_0e[((P[p][0] * 4 + P[p][1]) * 4 + P[p][2]) * 4 + k];
            float inv = (a == d) ? (1.f / 6.f) : ((a == b || b == d) ? 0.5f : 1.f);
            S3e[m][k] = acc * inv;
        } else if (t < 440) {
            int r = t - 80;
            int m = r / 18, j = r % 18, k = j / 3, i = j % 3;
            int a = TRI[m][0], b = TRI[m][1], d = TRI[m][2];
            int P[6][3] = {{a,b,d},{a,d,b},{b,a,d},{b,d,a},{d,a,b},{d,b,a}};
            float acc = 0.f;
#pragma unroll
            for (int p = 0; p < 6; ++p)
                acc += u3_1o[(((P[p][0] * 4 + P[p][1]) * 4 + P[p][2]) * 6 + k) * 3 + i];
            float inv = (a == d) ? (1.f / 6.f) : ((a == b || b == d) ? 0.5f : 1.f);
            S3o[m][k][i] = acc * inv;
        } else if (t < 460) {
            int r = t - 440;
            int m = r >> 1, k = r & 1;
            int a = PAIR[m][0], b = PAIR[m][1];
            float acc = u2_0e[(a * 4 + b) * 2 + k];
            if (a != b) acc += u2_0e[(b * 4 + a) * 2 + k];
            S2e[m][k] = acc;
        } else if (t < 520) {
            int r = t - 460;
            int m = r / 6, j = r % 6, k = j / 3, i = j % 3;
            int a = PAIR[m][0], b = PAIR[m][1];
            float acc = u2_1o[((a * 4 + b) * 2 + k) * 3 + i];
            if (a != b) acc += u2_1o[((b * 4 + a) * 2 + k) * 3 + i];
            S2o[m][k][i] = acc;
        } else if (t < 524) {
            int d = t - 520;
            S1e[d] = u1_0e[d];
        } else {
            int r = t - 524;
            S1o[r / 3][r % 3] = u1_1o[r];
        }
    }
    __syncthreads();

    // stage B: per (s,c) contraction with weights -> T rows
    int tg = (blockIdx.x - SB) * 256 + tid;              // 44*256 = 88*128
    int s = tg >> 7, c = tg & 127;

    float wk3e[4], wk3o[6], wk2e[2], wk2o[2];
#pragma unroll
    for (int k = 0; k < 4; ++k) wk3e[k] = w3_0e[(s * 4 + k) * CCH + c];
#pragma unroll
    for (int k = 0; k < 6; ++k) wk3o[k] = w3_1o[(s * 6 + k) * CCH + c];
#pragma unroll
    for (int k = 0; k < 2; ++k) wk2e[k] = w2_0e[(s * 2 + k) * CCH + c];
#pragma unroll
    for (int k = 0; k < 2; ++k) wk2o[k] = w2_1o[(s * 2 + k) * CCH + c];
    float wk1e = w1_0e[s * CCH + c];
    float wk1o = w1_1o[s * CCH + c];

    f32x4* Trow = reinterpret_cast<f32x4*>(T) + (size_t)s * 34 * CCH + c;  // row m at Trow[m*CCH]
#pragma unroll
    for (int m = 0; m < 20; ++m) {
        f32x4 row;
        float e = 0.f;
#pragma unroll
        for (int k = 0; k < 4; ++k) e = fmaf(S3e[m][k], wk3e[k], e);
        row.x = e;
#pragma unroll
        for (int i = 0; i < 3; ++i) {
            float o = 0.f;
#pragma unroll
            for (int k = 0; k < 6; ++k) o = fmaf(S3o[m][k][i], wk3o[k], o);
            row[1 + i] = o;
        }
        Trow[m * CCH] = row;
    }
#pragma unroll
    for (int m = 0; m < 10; ++m) {
        f32x4 row;
        row.x = fmaf(S2e[m][0], wk2e[0], S2e[m][1] * wk2e[1]);
#pragma unroll
        for (int i = 0; i < 3; ++i)
            row[1 + i] = fmaf(S2o[m][0][i], wk2o[0], S2o[m][1][i] * wk2o[1]);
        Trow[(20 + m) * CCH] = row;
    }
#pragma unroll
    for (int d = 0; d < 4; ++d) {
        f32x4 row;
        row.x = S1e[d] * wk1e;
#pragma unroll
        for (int i = 0; i < 3; ++i) row[1 + i] = S1o[d][i] * wk1o;
        Trow[(30 + d) * CCH] = row;
    }
}

// ---------------- kernel 2: inline scan + ballot-ranked scatter (verified R9/R10) ----------------

__global__ __launch_bounds__(256) void k_sB(
    const int* __restrict__ species, int N, const int* __restrict__ blockhist,
    int* __restrict__ counts, int* __restrict__ list) {
    __shared__ int boff[NS];
    __shared__ int wh[4][NS];
    int tid = threadIdx.x, b = blockIdx.x, lane = tid & 63, w = tid >> 6;
    for (int sp = tid; sp < NS; sp += 256) {
        int acc = 0;
        for (int b2 = 0; b2 < b; ++b2) acc += blockhist[b2 * NS + sp];
        boff[sp] = acc;
        if (b == SB - 1) counts[sp] = acc + blockhist[(SB - 1) * NS + sp];
    }
    for (int i = tid; i < 4 * NS; i += 256) ((int*)wh)[i] = 0;
    __syncthreads();
    int n = b * 256 + tid;
    int s = (n < N) ? species[n] : -1;
    if (s >= 0) atomicAdd(&wh[w][s], 1);
    unsigned v = (s >= 0) ? (unsigned)s : 127u;
    unsigned long long eq = ~0ull;
#pragma unroll
    for (int bit = 0; bit < 7; ++bit) {
        unsigned long long bb = __ballot((v >> bit) & 1);
        eq &= ((v >> bit) & 1) ? bb : ~bb;
    }
    int rank = __popcll(eq & ((1ull << lane) - 1));
    __syncthreads();
    if (s >= 0) {
#pragma unroll
        for (int w2 = 0; w2 < 3; ++w2) if (w2 < w) rank += wh[w2][s];
        list[s * BCAP + boff[s] + rank] = n;
    }
}

// ---------------- main kernel: LDS-resident coefficients, 8 atoms per ds_read ----------------
// Grid (NS, STR, 2): species s, atom stripe (AB=128 atoms), channel half g.
// Block 256 threads = 4 waves; wave h handles 8 atoms per round, lane = channel c64.
// LDS: T slice [34][64][4] = 34.8 KB -> 4 blocks/CU, 16 waves/CU.
// Inner loop: per m, ONE ds_read_b128 (coef) feeds 8 atoms x 4 comps = 32 FMAs,
// monomials recomputed from x (2 muls, CSE'd). x double-buffered one round ahead.

__global__ __launch_bounds__(256) void k_main(
    const float* __restrict__ x, const float* __restrict__ T,
    const int* __restrict__ list, const int* __restrict__ counts,
    float* __restrict__ out) {
    int s = blockIdx.x;
    int cnt = counts[s];
    int t0 = (int)blockIdx.y * AB;
    if (t0 >= cnt) return;
    int g = blockIdx.z;
    int tid = threadIdx.x;
    int c64 = tid & 63, h = tid >> 6;
    int cg = g * 64 + c64;                      // global channel
    int nvalid = cnt - t0;                      // may exceed AB; store predicate uses pos<nvalid, pos<AB

    __shared__ float coefs[34 * 64 * 4];        // 34,816 B
    __shared__ int bidx[AB];

    // stage T slice -> LDS (per-m contiguous 1 KB chunks of the g-half)
    {
        const f32x4* gsrc = reinterpret_cast<const f32x4*>(T) + (size_t)s * 34 * CCH + g * 64;
        f32x4* ldst = reinterpret_cast<f32x4*>(coefs);
        for (int i = tid; i < 34 * 64; i += 256) {
            int m = i >> 6, cc = i & 63;
            ldst[i] = gsrc[(size_t)m * CCH + cc];
        }
    }
    if (tid < AB) {
        int tt = t0 + tid;
        bidx[tid] = list[s * BCAP + (tt < cnt ? tt : cnt - 1)];
    }
    __syncthreads();

    const f32x4* cfs = reinterpret_cast<const f32x4*>(coefs);

    // monomial index tables (compile-time after unroll)
    constexpr int A3[20] = {0,0,0,0,0,0,0,0,0,0,1,1,1,1,1,1,2,2,2,3};
    constexpr int B3[20] = {0,0,0,0,1,1,1,2,2,3,1,1,1,2,2,3,2,2,3,3};
    constexpr int D3[20] = {0,1,2,3,1,2,3,2,3,3,1,2,3,2,3,3,2,3,3,3};
    constexpr int A2[10] = {0,0,0,0,1,1,1,2,2,3};
    constexpr int B2[10] = {0,1,2,3,1,2,3,2,3,3};

    auto load_round = [&](int r, f32x4* dst) {
#pragma unroll
        for (int j = 0; j < 8; ++j) {
            int pos = r * 32 + h * 8 + j;       // < 128 by construction
            int n = bidx[pos];
            dst[j] = __builtin_nontemporal_load(
                reinterpret_cast<const f32x4*>(x + (size_t)n * 512 + cg * 4));
        }
    };

    auto do_round = [&](int r, const f32x4* xr) {
        float acc[8][4];
#pragma unroll
        for (int j = 0; j < 8; ++j)
#pragma unroll
            for (int k = 0; k < 4; ++k) acc[j][k] = 0.f;

#pragma unroll
        for (int m = 0; m < 34; ++m) {
            f32x4 cf = cfs[m * 64 + c64];
#pragma unroll
            for (int j = 0; j < 8; ++j) {
                float mono;
                if (m < 20)      mono = xr[j][A3[m]] * xr[j][B3[m]] * xr[j][D3[m]];
                else if (m < 30) mono = xr[j][A2[m - 20]] * xr[j][B2[m - 20]];
                else             mono = xr[j][m - 30];
                acc[j][0] = fmaf(cf[0], mono, acc[j][0]);
                acc[j][1] = fmaf(cf[1], mono, acc[j][1]);
                acc[j][2] = fmaf(cf[2], mono, acc[j][2]);
                acc[j][3] = fmaf(cf[3], mono, acc[j][3]);
            }
        }
#pragma unroll
        for (int j = 0; j < 8; ++j) {
            int pos = r * 32 + h * 8 + j;
            if (pos < nvalid) {                 // wave-uniform per j
                int n = bidx[pos];
                float* orow = out + (size_t)n * 512;
                __builtin_nontemporal_store(acc[j][0], orow + cg);
                __builtin_nontemporal_store(acc[j][1], orow + CCH + 3 * cg + 0);
                __builtin_nontemporal_store(acc[j][2], orow + CCH + 3 * cg + 1);
                __builtin_nontemporal_store(acc[j][3], orow + CCH + 3 * cg + 2);
            }
        }
    };

    f32x4 xA[8], xB[8];
    load_round(0, xA);
    load_round(1, xB);
    do_round(0, xA);
    load_round(2, xA);
    do_round(1, xB);
    load_round(3, xB);
    do_round(2, xA);
    do_round(3, xB);
}

// ---------------- launch ----------------

extern "C" void kernel_launch(void* const* d_in, const int* in_sizes, int n_in,
                              void* d_out, int out_size, void* d_ws, size_t ws_size,
                              hipStream_t stream) {
    const float* x     = (const float*)d_in[0];
    const float* u1_0e = (const float*)d_in[1];
    const float* w1_0e = (const float*)d_in[2];
    const float* u1_1o = (const float*)d_in[3];
    const float* w1_1o = (const float*)d_in[4];
    const float* u2_0e = (const float*)d_in[5];
    const float* w2_0e = (const float*)d_in[6];
    const float* u2_1o = (const float*)d_in[7];
    const float* w2_1o = (const float*)d_in[8];
    const float* u3_0e = (const float*)d_in[9];
    const float* w3_0e = (const float*)d_in[10];
    const float* u3_1o = (const float*)d_in[11];
    const float* w3_1o = (const float*)d_in[12];
    const int*   spec  = (const int*)d_in[13];
    int N = in_sizes[13];
    float* out = (float*)d_out;

    char* ws = (char*)d_ws;
    float* T       = (float*)ws;                             // NS*34*CCH*4 floats (6.13 MB)
    size_t tbytes  = (size_t)NS * 34 * CCH * 4 * sizeof(float);
    int* list      = (int*)(ws + tbytes);                    // NS*BCAP ints
    int* counts    = list + (size_t)NS * BCAP;               // NS ints
    int* blockhist = counts + NS;                            // SB*NS ints

    k_sort1<<<SB + 44, 256, 0, stream>>>(
        spec, N,
        u1_0e, w1_0e, u1_1o, w1_1o,
        u2_0e, w2_0e, u2_1o, w2_1o,
        u3_0e, w3_0e, u3_1o, w3_1o,
        T, blockhist);
    k_sB<<<SB, 256, 0, stream>>>(spec, N, blockhist, counts, list);
    k_main<<<dim3(NS, STR, 2), 256, 0, stream>>>(x, T, list, counts, out);
}

// Round 12
// 45.985 us; speedup vs baseline: 1.7185x; 1.1686x over previous
//
#include <hip/hip_runtime.h>

#define NS    88     // species
#define CCH   128    // channels
#define BCAP  16384  // per-species bucket capacity
#define STR   6      // atom stripes of AB per species
#define AB    128    // atoms per k_main block

typedef float f32x4 __attribute__((ext_vector_type(4)));

__device__ const int TRI[20][3] = {
    {0,0,0},{0,0,1},{0,0,2},{0,0,3},{0,1,1},{0,1,2},{0,1,3},{0,2,2},{0,2,3},{0,3,3},
    {1,1,1},{1,1,2},{1,1,3},{1,2,2},{1,2,3},{1,3,3},
    {2,2,2},{2,2,3},{2,3,3},
    {3,3,3}};
__device__ const int PAIR[10][2] = {
    {0,0},{0,1},{0,2},{0,3},{1,1},{1,2},{1,3},{2,2},{2,3},{3,3}};

// ---------------- sort kernel: block s compacts its species bucket ----------------
// 1024 threads scan all N atoms in 16 ascending chunks; ballot-rank within wave,
// LDS wave totals -> in-order positions. Deterministic, ascending, atomic-free.

__global__ __launch_bounds__(1024) void k_sort(
    const int* __restrict__ species, int N,
    int* __restrict__ counts, int* __restrict__ list) {
    __shared__ int wh[16];
    int s = blockIdx.x;
    int tid = threadIdx.x, lane = tid & 63, w = tid >> 6;
    int* bucket = list + s * BCAP;
    int pos = 0;
    for (int base = 0; base < N; base += 1024) {
        int n = base + tid;
        bool m = (n < N) && (species[n] == s);
        unsigned long long b = __ballot(m);
        int rank = __popcll(b & ((1ull << lane) - 1));
        if (lane == 0) wh[w] = __popcll(b);
        __syncthreads();
        int wbase = 0, tot = 0;
#pragma unroll
        for (int i = 0; i < 16; ++i) { int v = wh[i]; if (i < w) wbase += v; tot += v; }
        if (m) bucket[pos + wbase + rank] = n;
        pos += tot;
        __syncthreads();
    }
    if (tid == 0) counts[s] = pos;
}

// ---------------- main kernel: inline coef build into LDS + 8-atom rounds ----------------
// Grid (NS, STR, 2): species s, stripe (AB atoms), channel half g. Block 256 = 4 waves.
// LDS: coefs[34][64][4] (34.8 KB) built in-block from U (stage A bases) x W (stage B).
// Atom loop: per m, one ds_read_b128 feeds 8 atoms x 4 comps; x double-buffered.

__global__ __launch_bounds__(256, 1) void k_main(
    const float* __restrict__ x,
    const int* __restrict__ list, const int* __restrict__ counts,
    const float* __restrict__ u1_0e, const float* __restrict__ w1_0e,
    const float* __restrict__ u1_1o, const float* __restrict__ w1_1o,
    const float* __restrict__ u2_0e, const float* __restrict__ w2_0e,
    const float* __restrict__ u2_1o, const float* __restrict__ w2_1o,
    const float* __restrict__ u3_0e, const float* __restrict__ w3_0e,
    const float* __restrict__ u3_1o, const float* __restrict__ w3_1o,
    float* __restrict__ out) {
    int s = blockIdx.x;
    int cnt = counts[s];
    int t0 = (int)blockIdx.y * AB;
    if (t0 >= cnt) return;                      // block-uniform
    int g = blockIdx.z;
    int tid = threadIdx.x;
    int c64 = tid & 63, h = tid >> 6;
    int cg = g * 64 + c64;
    int nvalid = cnt - t0;

    __shared__ float S3e[20][4];
    __shared__ float S3o[20][6][3];
    __shared__ float S2e[10][2];
    __shared__ float S2o[10][2][3];
    __shared__ float S1e[4];
    __shared__ float S1o[4][3];
    __shared__ float coefs[34 * 64 * 4];
    __shared__ int bidx[AB];

    // ---- stage A: symmetrized bases into LDS (536 jobs; verified R6/R11) ----
    for (int j = tid; j < 536; j += 256) {
        if (j < 80) {
            int m = j >> 2, k = j & 3;
            int a = TRI[m][0], b = TRI[m][1], d = TRI[m][2];
            int P[6][3] = {{a,b,d},{a,d,b},{b,a,d},{b,d,a},{d,a,b},{d,b,a}};
            float acc = 0.f;
#pragma unroll
            for (int p = 0; p < 6; ++p)
                acc += u3_0e[((P[p][0] * 4 + P[p][1]) * 4 + P[p][2]) * 4 + k];
            float inv = (a == d) ? (1.f / 6.f) : ((a == b || b == d) ? 0.5f : 1.f);
            S3e[m][k] = acc * inv;
        } else if (j < 440) {
            int r = j - 80;
            int m = r / 18, jj = r % 18, k = jj / 3, i = jj % 3;
            int a = TRI[m][0], b = TRI[m][1], d = TRI[m][2];
            int P[6][3] = {{a,b,d},{a,d,b},{b,a,d},{b,d,a},{d,a,b},{d,b,a}};
            float acc = 0.f;
#pragma unroll
            for (int p = 0; p < 6; ++p)
                acc += u3_1o[(((P[p][0] * 4 + P[p][1]) * 4 + P[p][2]) * 6 + k) * 3 + i];
            float inv = (a == d) ? (1.f / 6.f) : ((a == b || b == d) ? 0.5f : 1.f);
            S3o[m][k][i] = acc * inv;
        } else if (j < 460) {
            int r = j - 440;
            int m = r >> 1, k = r & 1;
            int a = PAIR[m][0], b = PAIR[m][1];
            float acc = u2_0e[(a * 4 + b) * 2 + k];
            if (a != b) acc += u2_0e[(b * 4 + a) * 2 + k];
            S2e[m][k] = acc;
        } else if (j < 520) {
            int r = j - 460;
            int m = r / 6, jj = r % 6, k = jj / 3, i = jj % 3;
            int a = PAIR[m][0], b = PAIR[m][1];
            float acc = u2_1o[((a * 4 + b) * 2 + k) * 3 + i];
            if (a != b) acc += u2_1o[((b * 4 + a) * 2 + k) * 3 + i];
            S2o[m][k][i] = acc;
        } else if (j < 524) {
            int d = j - 520;
            S1e[d] = u1_0e[d];
        } else {
            int r = j - 524;
            S1o[r / 3][r % 3] = u1_1o[r];
        }
    }
    if (tid < AB) {
        int tt = t0 + tid;
        bidx[tid] = list[s * BCAP + (tt < cnt ? tt : cnt - 1)];
    }
    __syncthreads();

    // ---- stage B: coefficients for (s, cg) straight into LDS; thread owns c64, m = h+4k ----
    {
        float wk3e[4], wk3o[6], wk2e[2], wk2o[2];
#pragma unroll
        for (int k = 0; k < 4; ++k) wk3e[k] = w3_0e[(s * 4 + k) * CCH + cg];
#pragma unroll
        for (int k = 0; k < 6; ++k) wk3o[k] = w3_1o[(s * 6 + k) * CCH + cg];
#pragma unroll
        for (int k = 0; k < 2; ++k) wk2e[k] = w2_0e[(s * 2 + k) * CCH + cg];
#pragma unroll
        for (int k = 0; k < 2; ++k) wk2o[k] = w2_1o[(s * 2 + k) * CCH + cg];
        float wk1e = w1_0e[s * CCH + cg];
        float wk1o = w1_1o[s * CCH + cg];

        for (int m = h; m < 34; m += 4) {
            f32x4 row;
            if (m < 20) {
                float e = 0.f;
#pragma unroll
                for (int k = 0; k < 4; ++k) e = fmaf(S3e[m][k], wk3e[k], e);
                row.x = e;
#pragma unroll
                for (int i = 0; i < 3; ++i) {
                    float o = 0.f;
#pragma unroll
                    for (int k = 0; k < 6; ++k) o = fmaf(S3o[m][k][i], wk3o[k], o);
                    row[1 + i] = o;
                }
            } else if (m < 30) {
                int mm = m - 20;
                row.x = fmaf(S2e[mm][0], wk2e[0], S2e[mm][1] * wk2e[1]);
#pragma unroll
                for (int i = 0; i < 3; ++i)
                    row[1 + i] = fmaf(S2o[mm][0][i], wk2o[0], S2o[mm][1][i] * wk2o[1]);
            } else {
                int d = m - 30;
                row.x = S1e[d] * wk1e;
#pragma unroll
                for (int i = 0; i < 3; ++i) row[1 + i] = S1o[d][i] * wk1o;
            }
            *reinterpret_cast<f32x4*>(&coefs[(m * 64 + c64) * 4]) = row;
        }
    }
    __syncthreads();

    const f32x4* cfs = reinterpret_cast<const f32x4*>(coefs);

    constexpr int A3[20] = {0,0,0,0,0,0,0,0,0,0,1,1,1,1,1,1,2,2,2,3};
    constexpr int B3[20] = {0,0,0,0,1,1,1,2,2,3,1,1,1,2,2,3,2,2,3,3};
    constexpr int D3[20] = {0,1,2,3,1,2,3,2,3,3,1,2,3,2,3,3,2,3,3,3};
    constexpr int A2[10] = {0,0,0,0,1,1,1,2,2,3};
    constexpr int B2[10] = {0,1,2,3,1,2,3,2,3,3};

    auto load_round = [&](int r, f32x4* dst) {
#pragma unroll
        for (int j = 0; j < 8; ++j) {
            int pos = r * 32 + h * 8 + j;
            int n = bidx[pos];
            dst[j] = __builtin_nontemporal_load(
                reinterpret_cast<const f32x4*>(x + (size_t)n * 512 + cg * 4));
        }
    };

    auto do_round = [&](int r, const f32x4* xr) {
        float acc[8][4];
#pragma unroll
        for (int j = 0; j < 8; ++j)
#pragma unroll
            for (int k = 0; k < 4; ++k) acc[j][k] = 0.f;

#pragma unroll
        for (int m = 0; m < 34; ++m) {
            f32x4 cf = cfs[m * 64 + c64];
#pragma unroll
            for (int j = 0; j < 8; ++j) {
                float mono;
                if (m < 20)      mono = xr[j][A3[m]] * xr[j][B3[m]] * xr[j][D3[m]];
                else if (m < 30) mono = xr[j][A2[m - 20]] * xr[j][B2[m - 20]];
                else             mono = xr[j][m - 30];
                acc[j][0] = fmaf(cf[0], mono, acc[j][0]);
                acc[j][1] = fmaf(cf[1], mono, acc[j][1]);
                acc[j][2] = fmaf(cf[2], mono, acc[j][2]);
                acc[j][3] = fmaf(cf[3], mono, acc[j][3]);
            }
        }
#pragma unroll
        for (int j = 0; j < 8; ++j) {
            int pos = r * 32 + h * 8 + j;
            if (pos < nvalid) {
                int n = bidx[pos];
                float* orow = out + (size_t)n * 512;
                __builtin_nontemporal_store(acc[j][0], orow + cg);
                __builtin_nontemporal_store(acc[j][1], orow + CCH + 3 * cg + 0);
                __builtin_nontemporal_store(acc[j][2], orow + CCH + 3 * cg + 1);
                __builtin_nontemporal_store(acc[j][3], orow + CCH + 3 * cg + 2);
            }
        }
    };

    int R = min(4, (min(nvalid, AB) + 31) >> 5);
    f32x4 xA[8], xB[8];
    load_round(0, xA);
    if (R > 1) load_round(1, xB);
    do_round(0, xA);
    if (R > 1) {
        if (R > 2) load_round(2, xA);
        do_round(1, xB);
        if (R > 2) {
            if (R > 3) load_round(3, xB);
            do_round(2, xA);
            if (R > 3) do_round(3, xB);
        }
    }
}

// ---------------- launch ----------------

extern "C" void kernel_launch(void* const* d_in, const int* in_sizes, int n_in,
                              void* d_out, int out_size, void* d_ws, size_t ws_size,
                              hipStream_t stream) {
    const float* x     = (const float*)d_in[0];
    const float* u1_0e = (const float*)d_in[1];
    const float* w1_0e = (const float*)d_in[2];
    const float* u1_1o = (const float*)d_in[3];
    const float* w1_1o = (const float*)d_in[4];
    const float* u2_0e = (const float*)d_in[5];
    const float* w2_0e = (const float*)d_in[6];
    const float* u2_1o = (const float*)d_in[7];
    const float* w2_1o = (const float*)d_in[8];
    const float* u3_0e = (const float*)d_in[9];
    const float* w3_0e = (const float*)d_in[10];
    const float* u3_1o = (const float*)d_in[11];
    const float* w3_1o = (const float*)d_in[12];
    const int*   spec  = (const int*)d_in[13];
    int N = in_sizes[13];
    float* out = (float*)d_out;

    char* ws = (char*)d_ws;
    int* list   = (int*)ws;                                  // NS*BCAP ints
    int* counts = list + (size_t)NS * BCAP;                  // NS ints

    k_sort<<<NS, 1024, 0, stream>>>(spec, N, counts, list);
    k_main<<<dim3(NS, STR, 2), 256, 0, stream>>>(
        x, list, counts,
        u1_0e, w1_0e, u1_1o, w1_1o,
        u2_0e, w2_0e, u2_1o, w2_1o,
        u3_0e, w3_0e, u3_1o, w3_1o,
        out);
}